// Round 6
// baseline (108.387 us; speedup 1.0000x reference)
//
#include <hip/hip_runtime.h>

// SE3 loss, round 11: RESUBMIT of round 10 (bench infra failed: "container
// failed twice" — no pytest/counters, so the d_ws-probe experiment never ran).
// Experiment: drop d_ws entirely to test whether the 268MB/41us
// fillBufferAligned workspace re-poison is conditional on touching d_ws.
// Single kernel, no K2: 512 blocks x 8 tiles (round-9's verified pipelined
// double-buffer body), same-address atomics kept SUBCRITICAL by splitting
// into two 512-atomic bursts: after tile 4 (hidden under tiles 5-8) and
// after tile 8 (~6us exposed tail). Round 2's lesson: 4096 atomics in one
// burst = 49us serialized; 2x512 spread ~= 6us exposed.
// If fills were conditional on ws use: dur_us -> ~65-78. If not: neutral ->
// harness floor reached.
//
// Math per element unchanged (verified, absmax 0.0):
//  - G (gt rotation): closed-form SVD polar factor of the unnormalized-quat
//    matrix: polar(G) = (c/r)I + ((1-c/r)/v^2) vv^T + (2w/r)[v]x.
//  - P (pred_R): 3 determinant-scaled Newton iterations + 1 unscaled polish;
//    sign(det0) flip folded into final iteration's coefficients.
//  - rot loss: ||P^T G - I||^2 == ||G - P||^2 (P orthogonal) — no matmul.

#define TILE 256
#define TPB_TILES 8
#define SCALED_ITERS 3
#define PLAIN_ITERS  1

__device__ __forceinline__ float se3_elem(const float* __restrict__ R,  // 9
                                          const float* __restrict__ Q,  // 7
                                          const float* __restrict__ T)  // 3
{
    float w  = Q[0], x = Q[1], y = Q[2], z = Q[3];

    // closed-form polar of quat matrix
    float v2 = x*x + y*y + z*z;
    float c  = 1.0f - 2.0f*v2;
    float r2 = fmaxf(c*c + 4.0f*(w*w)*v2, 1e-30f);
    float rr = __builtin_amdgcn_rsqf(r2);
    float ga = c * rr;
    float gt_ = (1.0f - ga) * __builtin_amdgcn_rcpf(fmaxf(v2, 1e-37f));
    float gb = 2.0f * w * rr;

    float tx = gt_*x, ty = gt_*y, tz = gt_*z;
    float bx = gb*x,  by = gb*y,  bz = gb*z;

    float G0 = ga + tx*x,  G1 = tx*y - bz,   G2 = tx*z + by;
    float G3 = tx*y + bz,  G4 = ga + ty*y,   G5 = ty*z - bx;
    float G6 = tx*z - by,  G7 = ty*z + bx,   G8 = ga + tz*z;

    // polar of pred_R: 3 scaled + 1 plain Newton iterations
    float X0 = R[0], X1 = R[1], X2 = R[2];
    float X3 = R[3], X4 = R[4], X5 = R[5];
    float X6 = R[6], X7 = R[7], X8 = R[8];

    float s = 1.0f;
#pragma unroll
    for (int it = 0; it < SCALED_ITERS + PLAIN_ITERS; ++it) {
        float C0 = X4*X8 - X5*X7;
        float C1 = X5*X6 - X3*X8;
        float C2 = X3*X7 - X4*X6;
        float C3 = X2*X7 - X1*X8;
        float C4 = X0*X8 - X2*X6;
        float C5 = X1*X6 - X0*X7;
        float C6 = X1*X5 - X2*X4;
        float C7 = X2*X3 - X0*X5;
        float C8 = X0*X4 - X1*X3;
        float det = X0*C0 + X1*C1 + X2*C2;
        if (it == 0) s = (det < 0.0f) ? -1.0f : 1.0f;
        float ka, kb;
        if (it < SCALED_ITERS) {
            float ad = fminf(fmaxf(fabsf(det), 1e-30f), 1e30f);
            float g  = __builtin_amdgcn_exp2f(0.33333333f * __builtin_amdgcn_logf(ad));
            ka = 0.5f * __builtin_amdgcn_rcpf(g);
            kb = 0.5f * g * __builtin_amdgcn_rcpf(det);
        } else {
            ka = 0.5f;
            kb = 0.5f * __builtin_amdgcn_rcpf(det);
        }
        if (it == SCALED_ITERS + PLAIN_ITERS - 1) { ka *= s; kb *= s; }
        X0 = ka*X0 + kb*C0;  X1 = ka*X1 + kb*C1;  X2 = ka*X2 + kb*C2;
        X3 = ka*X3 + kb*C3;  X4 = ka*X4 + kb*C4;  X5 = ka*X5 + kb*C5;
        X6 = ka*X6 + kb*C6;  X7 = ka*X7 + kb*C7;  X8 = ka*X8 + kb*C8;
    }

    float d0 = G0-X0, d1 = G1-X1, d2 = G2-X2;
    float d3 = G3-X3, d4 = G4-X4, d5 = G5-X5;
    float d6 = G6-X6, d7 = G7-X7, d8 = G8-X8;
    float rot = d0*d0 + d1*d1 + d2*d2
              + d3*d3 + d4*d4 + d5*d5
              + d6*d6 + d7*d7 + d8*d8;

    float e0 = T[0] - Q[4];
    float e1 = T[1] - Q[5];
    float e2 = T[2] - Q[6];
    float tl = e0*e0 + e1*e1 + e2*e2;

    return rot * (1.0f/9.0f) + tl * (1.0f/3.0f);   // 1/B applied by caller
}

__global__ __launch_bounds__(256) void se3_loss_kernel(
    const float* __restrict__ pred_R,
    const float* __restrict__ pred_t,
    const float* __restrict__ gt,
    float* __restrict__ out, int B, float invB)
{
    // Double-buffered tiles: 2 x 19456 B + 16 B.
    __shared__ __align__(16) float ldsR[2][TILE * 9];
    __shared__ __align__(16) float ldsQ[2][TILE * 7];
    __shared__ __align__(16) float ldsT[2][TILE * 3];
    __shared__ float wsums[4];

    const int tid    = threadIdx.x;
    const int ntiles = (B + TILE - 1) / TILE;
    const int tile0  = blockIdx.x * TPB_TILES;
    if (tile0 >= ntiles) return;

    float acc = 0.0f;

    // In-flight staging registers (tile t+1 rides here during compute of t).
    float4 r0, r1, r2, q0, q1, t0;

    auto load_tile = [&](int tile) {
        // Fully coalesced: per wave-load, 64 lanes x 16B contiguous.
        // Tail predicates wave-uniform (tid<64 -> wave 0; tid<192 -> w0-2).
        const float4* sR = reinterpret_cast<const float4*>(pred_R) + (size_t)tile * (TILE * 9 / 4);
        const float4* sQ = reinterpret_cast<const float4*>(gt)     + (size_t)tile * (TILE * 7 / 4);
        const float4* sT = reinterpret_cast<const float4*>(pred_t) + (size_t)tile * (TILE * 3 / 4);
        r0 = sR[tid];
        r1 = sR[tid + 256];
        if (tid < 64)  r2 = sR[tid + 512];
        q0 = sQ[tid];
        if (tid < 192) { q1 = sQ[tid + 256]; t0 = sT[tid]; }
    };
    auto store_tile = [&](int buf) {
        float4* dR = reinterpret_cast<float4*>(ldsR[buf]);
        float4* dQ = reinterpret_cast<float4*>(ldsQ[buf]);
        float4* dT = reinterpret_cast<float4*>(ldsT[buf]);
        dR[tid]       = r0;
        dR[tid + 256] = r1;
        if (tid < 64)  dR[tid + 512] = r2;
        dQ[tid]       = q0;
        if (tid < 192) { dQ[tid + 256] = q1; dT[tid] = t0; }
    };
    // Block-reduce v to thread 0. All threads call this (uniform barriers).
    auto block_reduce_to0 = [&](float v) -> float {
#pragma unroll
        for (int off = 32; off > 0; off >>= 1)
            v += __shfl_down(v, off, 64);
        int lane = tid & 63;
        int wid  = tid >> 6;
        if (lane == 0) wsums[wid] = v;
        __syncthreads();
        float r = 0.0f;
        if (tid == 0) r = wsums[0] + wsums[1] + wsums[2] + wsums[3];
        __syncthreads();   // wsums reusable after this
        return r;
    };

    const bool all_full = (tile0 + TPB_TILES) * TILE <= B;

    if (all_full) {
        // Pipelined path (the only path at B = 1048576):
        //   prologue: load(t0) -> LDS buf0 -> sync
        //   lt: issue-loads(t+1) || compute buf(lt&1) -> [mid-flush] -> sync ->
        //       write buf((lt+1)&1) -> sync
        load_tile(tile0);
        store_tile(0);
        __syncthreads();
#pragma unroll
        for (int lt = 0; lt < TPB_TILES; ++lt) {
            if (lt + 1 < TPB_TILES) load_tile(tile0 + lt + 1);
            const int buf = lt & 1;
            // LDS strides 9/7/3 floats (odd) -> <=2-way bank alias (free).
            acc += se3_elem(&ldsR[buf][9 * tid],
                            &ldsQ[buf][7 * tid],
                            &ldsT[buf][3 * tid]);
            if (lt == TPB_TILES / 2 - 1) {
                // Mid-kernel flush: 512-atomic burst (~6us serialized) hides
                // under the remaining 4 tiles of load+compute.
                float p = block_reduce_to0(acc * invB);
                if (tid == 0) atomicAdd(out, p);
                acc = 0.0f;
            }
            __syncthreads();   // everyone done reading buf before its sibling
                               // gets overwritten next iteration
            if (lt + 1 < TPB_TILES) {
                store_tile((lt + 1) & 1);
                __syncthreads();
            }
        }
        // Final flush (second 512-atomic burst, exposed tail only).
        float p = block_reduce_to0(acc * invB);
        if (tid == 0) atomicAdd(out, p);
    } else {
        // Ragged tail path (not taken at B = 1048576): per-tile scalar staging.
        for (int lt = 0; lt < TPB_TILES; ++lt) {
            const int tile = tile0 + lt;
            if (tile >= ntiles) break;
            const int base  = tile * TILE;
            int count = B - base;
            if (count > TILE) count = TILE;
            __syncthreads();
            for (int i = tid; i < count * 9; i += 256) ldsR[0][i] = pred_R[(size_t)base * 9 + i];
            for (int i = tid; i < count * 7; i += 256) ldsQ[0][i] = gt[(size_t)base * 7 + i];
            for (int i = tid; i < count * 3; i += 256) ldsT[0][i] = pred_t[(size_t)base * 3 + i];
            __syncthreads();
            if (tid < count)
                acc += se3_elem(&ldsR[0][9 * tid], &ldsQ[0][7 * tid], &ldsT[0][3 * tid]);
        }
        float p = block_reduce_to0(acc * invB);
        if (tid == 0) atomicAdd(out, p);
    }
}

extern "C" void kernel_launch(void* const* d_in, const int* in_sizes, int n_in,
                              void* d_out, int out_size, void* d_ws, size_t ws_size,
                              hipStream_t stream) {
    const float* pred_R = (const float*)d_in[0];
    const float* pred_t = (const float*)d_in[1];
    const float* gt     = (const float*)d_in[2];
    float* out = (float*)d_out;
    int B = in_sizes[0] / 9;

    hipMemsetAsync(out, 0, sizeof(float), stream);

    const int block  = 256;
    const int ntiles = (B + TILE - 1) / TILE;
    const int grid   = (ntiles + TPB_TILES - 1) / TPB_TILES;   // 512 blocks

    se3_loss_kernel<<<grid, block, 0, stream>>>(pred_R, pred_t, gt, out, B,
                                                1.0f / (float)B);
}